// Round 13
// baseline (286.523 us; speedup 1.0000x reference)
//
#include <hip/hip_runtime.h>
#include <cstdint>
#include <cstddef>

// R18: R15 champion structure with the output-feedback algebraically FOLDED:
//  - r,z gates: W_eff = W_hh + W_x2(x)W_out (rank-2), bias += W_x2.b_out --
//    exact fold, precomputed in k0. Step 0 corrected with W_x2.(a0 - xc0).
//  - n gate needs x_t itself: computed IN-GEMM by every block via
//    v_dot2_f32_f16 of the A-fragments (which already span all 512 h-cols)
//    against an LDS W_out copy -> the entire P exchange (buffers, publishes,
//    RFO, prologue load chain, 64-shfl reduce tree) is DELETED.
//  - dout[t-1] = xc computed at step t (LDS stash, cgrp0); out_11 via one
//    x-only pass over g_h[12] after the final barrier.
// Block-major h, warming, wave-private phases, 16-block ticket barrier: R15.

typedef __attribute__((ext_vector_type(8))) _Float16 f16x8;
typedef __attribute__((ext_vector_type(4))) float floatx4;
typedef _Float16 h2 __attribute__((ext_vector_type(2)));

__device__ unsigned g_cnt[8 * 64];     // per-XCD registration tickets
__device__ unsigned g_gbar[16 * 64];   // per-group barrier counters (padded)

// g_h[t]: [16 grp][16 cgrp][256 rows][32 cols] fp16, t=0..12 (13 x 4MB).
__device__ __align__(256) _Float16 g_h[13][16 * 16 * 256 * 32];

__device__ __forceinline__ float sigm_f(float v) { return 1.0f / (1.0f + __expf(-v)); }
__device__ __forceinline__ float tanh_f(float v) { return 2.0f / (1.0f + __expf(-2.0f * v)) - 1.0f; }

__device__ __forceinline__ void async16(void* lds, const void* g) {
    __builtin_amdgcn_global_load_lds(
        (const __attribute__((address_space(1))) void*)g,
        (__attribute__((address_space(3))) void*)lds, 16, 0, 0);
}

union H8 { f16x8 v; h2 p[4]; };

__device__ __forceinline__ void dot8(float& acc0, float& acc1,
                                     f16x8 a, f16x8 w0, f16x8 w1) {
#if __has_builtin(__builtin_amdgcn_fdot2)
    H8 ha{a}, hw0{w0}, hw1{w1};
    #pragma unroll
    for (int p = 0; p < 4; p++) {
        acc0 = __builtin_amdgcn_fdot2(ha.p[p], hw0.p[p], acc0, false);
        acc1 = __builtin_amdgcn_fdot2(ha.p[p], hw1.p[p], acc1, false);
    }
#else
    #pragma unroll
    for (int e = 0; e < 8; e++) {
        float av = (float)a[e];
        acc0 += av * (float)w0[e];
        acc1 += av * (float)w1[e];
    }
#endif
}

// Per-group barrier: EXACTLY 16 co-resident same-XCD blocks (validated).
__device__ __forceinline__ void group_barrier16(unsigned gidx) {
    asm volatile("s_waitcnt vmcnt(0)" ::: "memory");
    __syncthreads();
    if (threadIdx.x == 0) {
        unsigned* ctr = &g_gbar[gidx * 64];
        unsigned t = __hip_atomic_fetch_add(ctr, 1u, __ATOMIC_RELAXED,
                                            __HIP_MEMORY_SCOPE_AGENT);
        unsigned target = (t & ~15u) + 16u;
        while (__hip_atomic_load(ctr, __ATOMIC_RELAXED,
                                 __HIP_MEMORY_SCOPE_AGENT) < target)
            __builtin_amdgcn_s_sleep(1);
    }
    __syncthreads();
}

// ---------------- K0: casts + packing + a0 + WEIGHT FOLD ----------------
__global__ __launch_bounds__(256) void k0_prep(
    const float* __restrict__ z, const float* __restrict__ x,
    const float* __restrict__ x0, const float* __restrict__ W_ia,
    const float* __restrict__ b_ia, const float* __restrict__ W_ih,
    const float* __restrict__ W_hh, const float* __restrict__ W_h0,
    const float* __restrict__ W_out, const float* __restrict__ b_hh,
    const float* __restrict__ b_out,
    _Float16* __restrict__ zx16, _Float16* __restrict__ wcat16,
    _Float16* __restrict__ whh16, _Float16* __restrict__ wo16,
    float* __restrict__ pk, float* __restrict__ xbuf)
{
    const int ZX = 4096 * 256, WC = 2048 * 256, WH = 1536 * 512, PKN = 512,
              XB = 4096 * 2, WO = 1024;
    const int total = ZX + WC + WH + PKN + XB + WO;
    for (int idx = blockIdx.x * 256 + threadIdx.x; idx < total; idx += gridDim.x * 256) {
        if (idx < ZX) {
            int i = idx >> 8, k = idx & 255;
            float v = (k < 128) ? z[i * 128 + k] : x[i * 128 + (k - 128)];
            zx16[idx] = (_Float16)v;
        } else if (idx < ZX + WC) {
            int j = idx - ZX;
            int n = j >> 8, k = j & 255;
            float v = (n < 512) ? W_h0[n * 256 + k] : W_ih[(n - 512) * 258 + k];
            wcat16[j] = (_Float16)v;
        } else if (idx < ZX + WC + WH) {
            int j = idx - ZX - WC;
            int n = j >> 9, k = j & 511;
            float v = W_hh[j];
            if (n < 1024)   // fold rank-2 output feedback into r,z rows
                v += W_ih[n * 258 + 256] * W_out[k] +
                     W_ih[n * 258 + 257] * W_out[512 + k];
            whh16[j] = (_Float16)v;
        } else if (idx < ZX + WC + WH + PKN) {
            int jc = idx - ZX - WC - WH;
            float* o = pk + jc * 12;
            o[0] = W_ih[jc * 258 + 256];          o[1] = W_ih[jc * 258 + 257];
            o[2] = W_ih[(512 + jc) * 258 + 256];  o[3] = W_ih[(512 + jc) * 258 + 257];
            o[4] = W_ih[(1024 + jc) * 258 + 256]; o[5] = W_ih[(1024 + jc) * 258 + 257];
            // folded biases: bhr' = bhr + wxr.b_out ; bhz' = bhz + wxz.b_out
            o[6] = b_hh[jc] + o[0] * b_out[0] + o[1] * b_out[1];
            o[7] = b_hh[512 + jc] + o[2] * b_out[0] + o[3] * b_out[1];
            o[8] = b_hh[1024 + jc];
            o[9] = W_out[jc]; o[10] = W_out[512 + jc]; o[11] = 0.f;
        } else if (idx < ZX + WC + WH + PKN + XB) {
            int j = idx - ZX - WC - WH - PKN;
            int i = j >> 1, d = j & 1;
            float s = b_ia[d];
            #pragma unroll
            for (int k2 = 0; k2 < 4; k2++) s += x0[i * 4 + k2] * W_ia[d * 4 + k2];
            xbuf[j] = s;
        } else {
            int j = idx - ZX - WC - WH - PKN - XB;   // 0..1023
            wo16[j] = (_Float16)W_out[j];
        }
    }
}

// ---------------- K2: fused pre-GEMM + XCD-local persistent GRU ----------------
// LDS: B @0 (96KB), hstore[256][32]h @98304 (16KB), xs[8][32]f2 @114688 (2KB),
// douts[8][12][64]f @116736 (24KB), dummy @141312 (1KB), slot @142336,
// wout[2][512]h @142400 (2KB), xd[8][32]f2 @144448 (2KB). Total 146496.
__global__ __launch_bounds__(512, 2) void k2_fused(
    const _Float16* __restrict__ zx16, const _Float16* __restrict__ wcat16,
    const _Float16* __restrict__ whh16, const float* __restrict__ pk,
    const float* __restrict__ xbuf, const float* __restrict__ b_h0,
    const float* __restrict__ b_ih, const _Float16* __restrict__ wo16g,
    const float* __restrict__ b_out, float* __restrict__ dout)
{
    extern __shared__ __align__(16) char smem[];
    const uint32_t BOFF = 0, HST = 98304, XSO = 114688, DOUT = 116736,
                   DUM = 141312, SLO = 142336, WOUT = 142400, XDO = 144448;
    const int tid = threadIdx.x;
    float* douts = (float*)(smem + DOUT);

    // ---- XCD discovery + registration (1 blk/CU => exactly 32 blks/XCD) ----
    unsigned xcc;
    asm volatile("s_getreg_b32 %0, hwreg(HW_REG_XCC_ID)" : "=s"(xcc));
    xcc &= 7u;
    if (tid == 0) {
        unsigned s = __hip_atomic_fetch_add(&g_cnt[xcc * 64], 1u, __ATOMIC_RELAXED,
                                            __HIP_MEMORY_SCOPE_AGENT) & 31u;
        *(unsigned*)(smem + SLO) = s;
    }
    // stage W_out fp16 into LDS (1024 halves)
    if (tid < 128) {
        f16x8 v = *(const f16x8*)(wo16g + tid * 8);
        *(f16x8*)(smem + WOUT + (uint32_t)tid * 16) = v;
    }
    __syncthreads();
    const unsigned slot = *(volatile unsigned*)(smem + SLO);
    const int shalf = slot >> 4, cgrp = slot & 15;
    const unsigned gidx = xcc * 2 + shalf;      // 0..15, 16 blocks each
    const int M0g = (int)gidx * 256;            // group's global sample base
    const int jc0 = cgrp * 32;                  // block's 32 h-cols (x3 gates)

    const int wv = tid >> 6, lane = tid & 63;
    const int l15 = lane & 15, q2 = lane >> 4;

    // ---- warm g_h[0] own slab (one-time RFO prefetch) ----
    if (wv == 0) {
        const char* wb = (const char*)&g_h[0][0] + (size_t)gidx * 262144 +
                         (size_t)cgrp * 16384 + (size_t)lane * 128;
        async16(smem + DUM, wb);
        async16(smem + DUM, wb + 8192);
    }

    // ---- stage pre-B: 128 rows x 256 fp16 (512B) from wcat16 [R12/R15] ----
    #pragma unroll
    for (int j2 = 0; j2 < 8; j2++) {
        int p = j2 * 8 + wv;              // 0..63 (wave-uniform)
        int r0 = p * 2;
        int r = r0 + (lane >> 5);
        int s = lane & 31;
        int n = (r < 96) ? (512 + (r >> 5) * 512 + jc0 + (r & 31))
                         : (jc0 + (r - 96));
        const _Float16* src = wcat16 + (size_t)n * 256 + ((s ^ (r & 15)) << 3);
        async16(smem + (uint32_t)r0 * 512, src);
    }

    // ---- t-invariant params ----
    float4 p0v[2], p1v[2], p2v[2];
    float bih[3][2], bh0[2];
    #pragma unroll
    for (int jt = 0; jt < 2; jt++) {
        int jc = jc0 + jt * 16 + l15;
        const float4* pkp = (const float4*)(pk + (size_t)jc * 12);
        p0v[jt] = pkp[0]; p1v[jt] = pkp[1]; p2v[jt] = pkp[2];
        bh0[jt] = b_h0[jc];
        #pragma unroll
        for (int g = 0; g < 3; g++) bih[g][jt] = b_ih[g * 512 + jc];
    }
    const float bo0 = b_out[0], bo1 = b_out[1];

    uint32_t bbase[6];   // steady B (96 rows x 1024B) [validated swizzle]
    #pragma unroll
    for (int g = 0; g < 3; g++)
        #pragma unroll
        for (int jt = 0; jt < 2; jt++) {
            int r = g * 32 + jt * 16 + l15;
            bbase[g * 2 + jt] = BOFF + (uint32_t)r * 1024 +
                                ((uint32_t)(q2 ^ (r & 3)) << 4) +
                                ((uint32_t)((r >> 2) & 3) << 6);
        }
    uint32_t pb[8];      // pre-B (128 rows x 512B): 0..5 gates, 6..7 h0
    #pragma unroll
    for (int sl = 0; sl < 8; sl++) {
        int r = (sl < 6) ? ((sl >> 1) * 32 + (sl & 1) * 16 + l15)
                         : (96 + (sl - 6) * 16 + l15);
        pb[sl] = BOFF + (uint32_t)r * 512 +
                 ((uint32_t)(q2 ^ (r & 3)) << 4) +
                 ((uint32_t)((r >> 2) & 3) << 6);
    }
    __syncthreads();   // pre-B staged (barrier drains vmcnt)

    // ---- pre-GEMM: K=256, A=zx16, 8 ks, depth-3 queue [R12 verbatim] ----
    const char* zp0 = (const char*)zx16 +
        ((size_t)(M0g + (wv * 2 + 0) * 16 + l15) * 256) * 2 + (size_t)q2 * 16;
    const char* zp1 = (const char*)zx16 +
        ((size_t)(M0g + (wv * 2 + 1) * 16 + l15) * 256) * 2 + (size_t)q2 * 16;
    floatx4 accP[2][8];
    #pragma unroll
    for (int mt = 0; mt < 2; mt++)
        #pragma unroll
        for (int sl = 0; sl < 8; sl++) accP[mt][sl] = (floatx4){0.f, 0.f, 0.f, 0.f};
    {
        f16x8 aq[4][2];
        #define ALOADZ(S, KS) do { \
            aq[S][0] = *(const f16x8*)(zp0 + (KS) * 64); \
            aq[S][1] = *(const f16x8*)(zp1 + (KS) * 64); \
        } while (0)
        ALOADZ(0, 0); ALOADZ(1, 1); ALOADZ(2, 2);
        #pragma unroll
        for (int ks = 0; ks < 8; ks++) {
            if (ks < 5) { ALOADZ((ks + 3) & 3, ks + 3); }
            f16x8 a0 = aq[ks & 3][0];
            f16x8 a1 = aq[ks & 3][1];
            const uint32_t kadd = (uint32_t)((ks >> 2) << 8);
            const uint32_t kxor = (uint32_t)((ks & 3) << 6);
            #pragma unroll
            for (int sl = 0; sl < 8; sl++) {
                f16x8 b = *(const f16x8*)(smem + ((pb[sl] + kadd) ^ kxor));
                accP[0][sl] = __builtin_amdgcn_mfma_f32_16x16x32_f16(a0, b, accP[0][sl], 0, 0, 0);
                accP[1][sl] = __builtin_amdgcn_mfma_f32_16x16x32_f16(a1, b, accP[1][sl], 0, 0, 0);
            }
        }
        #undef ALOADZ
    }

    // ---- gi -> registers (+bias); h0 -> hstore ----
    float gi[2][3][2][4];
    #pragma unroll
    for (int mt = 0; mt < 2; mt++)
        #pragma unroll
        for (int g = 0; g < 3; g++)
            #pragma unroll
            for (int jt = 0; jt < 2; jt++)
                #pragma unroll
                for (int reg = 0; reg < 4; reg++)
                    gi[mt][g][jt][reg] = accP[mt][g * 2 + jt][reg] + bih[g][jt];
    #pragma unroll
    for (int mt = 0; mt < 2; mt++)
        #pragma unroll
        for (int jt = 0; jt < 2; jt++)
            #pragma unroll
            for (int reg = 0; reg < 4; reg++) {
                int rl = (wv * 2 + mt) * 16 + q2 * 4 + reg;
                float v = accP[mt][6 + jt][reg] + bh0[jt];
                *(_Float16*)(smem + HST + (uint32_t)(rl * 64 + (jt * 16 + l15) * 2)) = (_Float16)v;
            }
    __syncthreads();   // pre-B reads + hstore writes complete

    // ---- stage W_eff/W_hh (96 rows x 512 = 96KB) ----
    #pragma unroll
    for (int j = 0; j < 12; j++) {
        int r = j * 8 + wv;               // 0..95
        int n = (r >> 5) * 512 + jc0 + (r & 31);
        const _Float16* src = whh16 + (size_t)n * 512 + ((lane ^ (r & 15)) << 3);
        async16(smem + BOFF + (uint32_t)r * 1024, src);
    }
    // ---- publish h0 (block-major, contiguous own lines) ----
    {
        int row = tid >> 1, half = tid & 1;
        const char* sl = smem + HST + (uint32_t)(row * 64 + half * 32);
        char* gd = (char*)&g_h[0][0] + (size_t)gidx * 262144 + (size_t)cgrp * 16384 +
                   (size_t)row * 64 + (size_t)half * 32;
        *(f16x8*)gd = *(const f16x8*)sl;
        *(f16x8*)(gd + 16) = *(const f16x8*)(sl + 16);
    }
    group_barrier16(gidx);   // drains W staging + h0 publish

    // ---- 12-step loop: no mid-step __syncthreads ----
    #pragma unroll 1
    for (int t = 0; t < 12; t++) {
        // warm next h publish region (RFO prefetch under GEMM)
        if (wv == 0) {
            const char* wb = (const char*)&g_h[t + 1][0] + (size_t)gidx * 262144 +
                             (size_t)cgrp * 16384 + (size_t)lane * 128;
            async16(smem + DUM, wb);
            async16(smem + DUM, wb + 8192);
        }

        // GEMM: K=512, A from g_h[t] (block-major: ks slab = 16KB) + in-GEMM x
        const char* hb = (const char*)&g_h[t][0] + (size_t)gidx * 262144 + (size_t)q2 * 16;
        const char* rp0 = hb + (size_t)((wv * 2 + 0) * 16 + l15) * 64;
        const char* rp1 = hb + (size_t)((wv * 2 + 1) * 16 + l15) * 64;
        floatx4 acc[2][3][2];
        #pragma unroll
        for (int mt = 0; mt < 2; mt++)
            #pragma unroll
            for (int g = 0; g < 3; g++)
                #pragma unroll
                for (int jt = 0; jt < 2; jt++)
                    acc[mt][g][jt] = (floatx4){0.f, 0.f, 0.f, 0.f};
        float xacc[2][2] = {{0.f, 0.f}, {0.f, 0.f}};

        f16x8 aq[4][2];
        #define ALOAD(S, KS) do { \
            aq[S][0] = *(const f16x8*)(rp0 + (size_t)(KS) * 16384); \
            aq[S][1] = *(const f16x8*)(rp1 + (size_t)(KS) * 16384); \
        } while (0)
        ALOAD(0, 0); ALOAD(1, 1); ALOAD(2, 2);
        #pragma unroll
        for (int ks = 0; ks < 16; ks++) {
            if (ks < 13) { ALOAD((ks + 3) & 3, ks + 3); }
            f16x8 a0 = aq[ks & 3][0];
            f16x8 a1 = aq[ks & 3][1];
            const uint32_t kadd = (uint32_t)((ks >> 2) << 8);
            const uint32_t kxor = (uint32_t)((ks & 3) << 6);
            #pragma unroll
            for (int g = 0; g < 3; g++)
                #pragma unroll
                for (int jt = 0; jt < 2; jt++) {
                    f16x8 b = *(const f16x8*)(smem + ((bbase[g * 2 + jt] + kadd) ^ kxor));
                    acc[0][g][jt] = __builtin_amdgcn_mfma_f32_16x16x32_f16(a0, b, acc[0][g][jt], 0, 0, 0);
                    acc[1][g][jt] = __builtin_amdgcn_mfma_f32_16x16x32_f16(a1, b, acc[1][g][jt], 0, 0, 0);
                }
            // x_t partial dot: thread's 8 cols of this ks-slab
            f16x8 w0v = *(const f16x8*)(smem + WOUT + (uint32_t)(ks * 64 + q2 * 16));
            f16x8 w1v = *(const f16x8*)(smem + WOUT + 1024u + (uint32_t)(ks * 64 + q2 * 16));
            dot8(xacc[0][0], xacc[0][1], a0, w0v, w1v);
            dot8(xacc[1][0], xacc[1][1], a1, w0v, w1v);
        }
        #undef ALOAD

        // ---- finish x: reduce over q2, +b_out; write xs/xd; stash dout ----
        #pragma unroll
        for (int mt = 0; mt < 2; mt++)
            #pragma unroll
            for (int d = 0; d < 2; d++) {
                xacc[mt][d] += __shfl_xor(xacc[mt][d], 16);
                xacc[mt][d] += __shfl_xor(xacc[mt][d], 32);
            }
        float xc[2][2];
        xc[0][0] = xacc[0][0] + bo0; xc[0][1] = xacc[0][1] + bo1;
        xc[1][0] = xacc[1][0] + bo0; xc[1][1] = xacc[1][1] + bo1;
        if (q2 == 0) {
            #pragma unroll
            for (int mt = 0; mt < 2; mt++) {
                int local = mt * 16 + l15;
                if (t == 0) {
                    float a00 = xbuf[(size_t)(M0g + wv * 32 + local) * 2 + 0];
                    float a01 = xbuf[(size_t)(M0g + wv * 32 + local) * 2 + 1];
                    ((float2*)(smem + XSO))[wv * 32 + local] = make_float2(a00, a01);
                    ((float2*)(smem + XDO))[wv * 32 + local] =
                        make_float2(a00 - xc[mt][0], a01 - xc[mt][1]);
                } else {
                    ((float2*)(smem + XSO))[wv * 32 + local] = make_float2(xc[mt][0], xc[mt][1]);
                    if (cgrp == 0)
                        ((float2*)douts)[wv * 384 + (t - 1) * 32 + local] =
                            make_float2(xc[mt][0], xc[mt][1]);
                }
            }
        }

        // ---- epilogue (wave-private rows): gates, hn -> hstore ----
        #pragma unroll
        for (int mt = 0; mt < 2; mt++) {
            #pragma unroll
            for (int jt = 0; jt < 2; jt++) {
                #pragma unroll
                for (int reg = 0; reg < 4; reg++) {
                    int local = mt * 16 + q2 * 4 + reg;        // 0..31 in wave
                    int rl = wv * 32 + local;                  // 0..255 in block
                    float2 xv = ((const float2*)(smem + XSO))[wv * 32 + local];
                    _Float16* hp = (_Float16*)(smem + HST + (uint32_t)(rl * 64 + (jt * 16 + l15) * 2));
                    float hold = (float)hp[0];
                    float rpre = gi[mt][0][jt][reg] + acc[mt][0][jt][reg] + p1v[jt].z;
                    float upre = gi[mt][1][jt][reg] + acc[mt][1][jt][reg] + p1v[jt].w;
                    if (t == 0) {
                        float2 xdv = ((const float2*)(smem + XDO))[wv * 32 + local];
                        rpre += p0v[jt].x * xdv.x + p0v[jt].y * xdv.y;
                        upre += p0v[jt].z * xdv.x + p0v[jt].w * xdv.y;
                    }
                    float r = sigm_f(rpre);
                    float u = sigm_f(upre);
                    float nn = tanh_f(gi[mt][2][jt][reg] + p1v[jt].x * xv.x + p1v[jt].y * xv.y +
                                      r * (acc[mt][2][jt][reg] + p2v[jt].x));
                    float hn = (1.f - u) * nn + u * hold;
                    hp[0] = (_Float16)hn;
                }
            }
        }

        // ---- publish h[t+1] (wave-private 2KB slice, block-major contiguous) ----
        {
            int row = tid >> 1, half = tid & 1;
            const char* sl = smem + HST + (uint32_t)(row * 64 + half * 32);
            char* gd = (char*)&g_h[t + 1][0] + (size_t)gidx * 262144 +
                       (size_t)cgrp * 16384 + (size_t)row * 64 + (size_t)half * 32;
            *(f16x8*)gd = *(const f16x8*)sl;
            *(f16x8*)(gd + 16) = *(const f16x8*)(sl + 16);
        }
        group_barrier16(gidx);
    }

    // ---- final: out_11 from g_h[12] (x-only pass) + dout flush, cgrp0 only ----
    if (cgrp == 0) {
        const char* hb = (const char*)&g_h[12][0] + (size_t)gidx * 262144 + (size_t)q2 * 16;
        const char* rp0 = hb + (size_t)((wv * 2 + 0) * 16 + l15) * 64;
        const char* rp1 = hb + (size_t)((wv * 2 + 1) * 16 + l15) * 64;
        float xa[2][2] = {{0.f, 0.f}, {0.f, 0.f}};
        #pragma unroll
        for (int ks = 0; ks < 16; ks++) {
            f16x8 a0 = *(const f16x8*)(rp0 + (size_t)ks * 16384);
            f16x8 a1 = *(const f16x8*)(rp1 + (size_t)ks * 16384);
            f16x8 w0v = *(const f16x8*)(smem + WOUT + (uint32_t)(ks * 64 + q2 * 16));
            f16x8 w1v = *(const f16x8*)(smem + WOUT + 1024u + (uint32_t)(ks * 64 + q2 * 16));
            dot8(xa[0][0], xa[0][1], a0, w0v, w1v);
            dot8(xa[1][0], xa[1][1], a1, w0v, w1v);
        }
        #pragma unroll
        for (int mt = 0; mt < 2; mt++)
            #pragma unroll
            for (int d = 0; d < 2; d++) {
                xa[mt][d] += __shfl_xor(xa[mt][d], 16);
                xa[mt][d] += __shfl_xor(xa[mt][d], 32);
            }
        if (q2 == 0) {
            #pragma unroll
            for (int mt = 0; mt < 2; mt++) {
                int local = mt * 16 + l15;
                ((float2*)douts)[wv * 384 + 11 * 32 + local] =
                    make_float2(xa[mt][0] + bo0, xa[mt][1] + bo1);
            }
        }
        // flush (wave-private region; LDS write->read within wave)
        size_t i = (size_t)M0g + wv * 32 + (lane >> 1);
        int d = lane & 1;
        #pragma unroll
        for (int tt = 0; tt < 12; tt++)
            dout[(i * 12 + tt) * 2 + d] = douts[wv * 768 + tt * 64 + lane];
    }
}

extern "C" void kernel_launch(void* const* d_in, const int* in_sizes, int n_in,
                              void* d_out, int out_size, void* d_ws, size_t ws_size,
                              hipStream_t stream)
{
    const float* z     = (const float*)d_in[0];
    const float* x     = (const float*)d_in[1];
    const float* x0    = (const float*)d_in[2];
    const float* W_ia  = (const float*)d_in[3];
    const float* b_ia  = (const float*)d_in[4];
    const float* W_h0  = (const float*)d_in[5];
    const float* b_h0  = (const float*)d_in[6];
    const float* W_ih  = (const float*)d_in[7];
    const float* b_ih  = (const float*)d_in[8];
    const float* W_hh  = (const float*)d_in[9];
    const float* b_hh  = (const float*)d_in[10];
    const float* W_out = (const float*)d_in[11];
    const float* b_out = (const float*)d_in[12];
    float* dout = (float*)d_out;

    char* ws = (char*)d_ws;
    _Float16* zx16   = (_Float16*)(ws + 20971520);   // 2 MiB
    _Float16* wcat16 = (_Float16*)(ws + 23068672);   // 1 MiB
    _Float16* whh16  = (_Float16*)(ws + 24117248);   // 1.5 MiB (W_eff folded)
    float*    pk     = (float*)(ws + 25690112);      // 24 KiB
    float*    xbuf   = (float*)(ws + 25714688);      // 32 KiB
    _Float16* wo16   = (_Float16*)(ws + 25747456);   // 2 KiB

    static bool s_attr_done = false;
    if (!s_attr_done) {
        hipFuncSetAttribute((const void*)k2_fused,
                            hipFuncAttributeMaxDynamicSharedMemorySize, 146496);
        s_attr_done = true;
    }

    k0_prep<<<2048, 256, 0, stream>>>(z, x, x0, W_ia, b_ia, W_ih, W_hh, W_h0,
                                      W_out, b_hh, b_out,
                                      zx16, wcat16, whh16, wo16, pk, xbuf);
    k2_fused<<<256, 512, 146496, stream>>>(zx16, wcat16, whh16, pk, xbuf,
                                           b_h0, b_ih, wo16, b_out, dout);
}

// Round 14
// 267.822 us; speedup vs baseline: 1.0698x; 1.0698x over previous
//
#include <hip/hip_runtime.h>
#include <cstdint>
#include <cstddef>

// R19: SINGLE-KERNEL fusion of the R15 champion. k0 deleted: every block
// generates all its inputs directly from the raw f32 tensors (no cross-block
// producer/consumer): steady-B/pre-B staged via read-f32 -> cvt -> swizzled
// ds_write at the IDENTICAL LDS layout the validated async16 staging produced;
// pre-GEMM A loads z/x f32 + converts in-register (same RNE cast as k0 ->
// bit-identical numerics); pk/a0/biases are scalar f32 loads. Step loop,
// P exchange, warming, wave-private phases, 16-block ticket barrier: R15
// verbatim. 1 launch instead of 2 -> removes ~50-60us of boundary time.

typedef __attribute__((ext_vector_type(8))) _Float16 f16x8;
typedef __attribute__((ext_vector_type(4))) float floatx4;

__device__ unsigned g_cnt[8 * 64];     // per-XCD registration tickets
__device__ unsigned g_gbar[16 * 64];   // per-group barrier counters (padded)

// Block-major exchange buffers (outside workspace; step-indexed => fresh
// addresses within a launch, validated R10-R15):
// g_h[t]: [16 grp][16 cgrp][256 rows][32 cols] fp16 (cgrp slab = 16KB).
// g_P[t]: [16 grp][16 cgrp][512] f32 (block slab = 2KB).
__device__ __align__(256) _Float16 g_h[12][16 * 16 * 256 * 32];
__device__ __align__(256) float    g_P[12][16 * 16 * 512];

__device__ __forceinline__ float sigm_f(float v) { return 1.0f / (1.0f + __expf(-v)); }
__device__ __forceinline__ float tanh_f(float v) { return 2.0f / (1.0f + __expf(-2.0f * v)) - 1.0f; }

__device__ __forceinline__ void async16(void* lds, const void* g) {
    __builtin_amdgcn_global_load_lds(
        (const __attribute__((address_space(1))) void*)g,
        (__attribute__((address_space(3))) void*)lds, 16, 0, 0);
}

// Load 8 cols of the virtual zx row i (cols 0..127 = z, 128..255 = x) as fp16.
// c is a multiple of 8 and never straddles the 128 seam.
__device__ __forceinline__ f16x8 ldzx8(const float* __restrict__ z,
                                       const float* __restrict__ x,
                                       int i, int c) {
    const float* s = (c < 128) ? (z + (size_t)i * 128 + c)
                               : (x + (size_t)i * 128 + (c - 128));
    float4 a = ((const float4*)s)[0], b = ((const float4*)s)[1];
    return (f16x8){(_Float16)a.x, (_Float16)a.y, (_Float16)a.z, (_Float16)a.w,
                   (_Float16)b.x, (_Float16)b.y, (_Float16)b.z, (_Float16)b.w};
}

// Per-group barrier: EXACTLY 16 co-resident same-XCD blocks (validated R11-R15).
__device__ __forceinline__ void group_barrier16(unsigned gidx) {
    asm volatile("s_waitcnt vmcnt(0)" ::: "memory");
    __syncthreads();
    if (threadIdx.x == 0) {
        unsigned* ctr = &g_gbar[gidx * 64];
        unsigned t = __hip_atomic_fetch_add(ctr, 1u, __ATOMIC_RELAXED,
                                            __HIP_MEMORY_SCOPE_AGENT);
        unsigned target = (t & ~15u) + 16u;
        while (__hip_atomic_load(ctr, __ATOMIC_RELAXED,
                                 __HIP_MEMORY_SCOPE_AGENT) < target)
            __builtin_amdgcn_s_sleep(1);
    }
    __syncthreads();
}

// ---------------- K: fully fused (prep + pre-GEMM + 12-step GRU) ----------------
// LDS: B @0 (96KB steady; 64KB pre-phase overlap), hstore[256][32]h @98304
// (16KB), xs[8][64]f @114688 (2KB), douts[8][12][64]f @116736 (24KB),
// dummy @141312 (1KB), slot @142336. Request 142400 (>80KB => 1 blk/CU).
__global__ __launch_bounds__(512, 2) void k_all(
    const float* __restrict__ z, const float* __restrict__ x,
    const float* __restrict__ x0, const float* __restrict__ W_ia,
    const float* __restrict__ b_ia, const float* __restrict__ W_h0,
    const float* __restrict__ b_h0, const float* __restrict__ W_ih,
    const float* __restrict__ b_ih, const float* __restrict__ W_hh,
    const float* __restrict__ b_hh, const float* __restrict__ W_out,
    const float* __restrict__ b_out, float* __restrict__ dout)
{
    extern __shared__ __align__(16) char smem[];
    const uint32_t BOFF = 0, HST = 98304, XSO = 114688, DOUT = 116736,
                   DUM = 141312, SLO = 142336;
    const int tid = threadIdx.x;
    float* xs = (float*)(smem + XSO);
    float* douts = (float*)(smem + DOUT);

    // ---- XCD discovery + registration (1 blk/CU => exactly 32 blks/XCD) ----
    unsigned xcc;
    asm volatile("s_getreg_b32 %0, hwreg(HW_REG_XCC_ID)" : "=s"(xcc));
    xcc &= 7u;
    if (tid == 0) {
        unsigned s = __hip_atomic_fetch_add(&g_cnt[xcc * 64], 1u, __ATOMIC_RELAXED,
                                            __HIP_MEMORY_SCOPE_AGENT) & 31u;
        *(unsigned*)(smem + SLO) = s;
    }
    __syncthreads();
    const unsigned slot = *(volatile unsigned*)(smem + SLO);
    const int shalf = slot >> 4, cgrp = slot & 15;
    const unsigned gidx = xcc * 2 + shalf;      // 0..15, 16 blocks each
    const int M0g = (int)gidx * 256;            // group's global sample base
    const int jc0 = cgrp * 32;                  // block's 32 h-cols (x3 gates)

    const int wv = tid >> 6, lane = tid & 63;
    const int l15 = lane & 15, q2 = lane >> 4;

    // ---- warm g_h[0] + g_P[0] own regions (one-time RFO prefetch) [R15] ----
    if (wv == 0) {
        const char* wb = (const char*)&g_h[0][0] + (size_t)gidx * 262144 +
                         (size_t)cgrp * 16384 + (size_t)lane * 128;
        async16(smem + DUM, wb);
        async16(smem + DUM, wb + 8192);
    }
    if (wv == 1) {
        const char* wp = (const char*)&g_P[0][0] +
                         ((size_t)gidx * 8192 + (size_t)cgrp * 512) * 4 +
                         (size_t)(lane & 15) * 128;
        async16(smem + DUM, wp);
    }

    // ---- inline pre-B staging: 128 rows x 256 fp16 (512B rows) from f32 ----
    // LDS[r*512 + s*16] = wcat_row(r)[ (s^(r&15))*8 ..+8 ] as fp16 -- identical
    // layout to the validated async16-based staging (R12/R15).
    #pragma unroll
    for (int u = 0; u < 8; u++) {
        int sl2 = u * 512 + tid;            // 0..4095
        int r = sl2 >> 5, s = sl2 & 31;     // row 0..127, slot 0..31
        int c = (s ^ (r & 15)) << 3;        // col base, multiple of 8
        f16x8 v;
        if (r < 96) {
            int nrow = (r >> 5) * 512 + jc0 + (r & 31);     // W_ih row
            const float2* src = (const float2*)(W_ih + (size_t)nrow * 258 + c);
            float2 a0 = src[0], a1 = src[1], a2 = src[2], a3 = src[3];
            v = (f16x8){(_Float16)a0.x, (_Float16)a0.y, (_Float16)a1.x, (_Float16)a1.y,
                        (_Float16)a2.x, (_Float16)a2.y, (_Float16)a3.x, (_Float16)a3.y};
        } else {
            int nrow = jc0 + (r - 96);                      // W_h0 row
            const float4* src = (const float4*)(W_h0 + (size_t)nrow * 256 + c);
            float4 a = src[0], b = src[1];
            v = (f16x8){(_Float16)a.x, (_Float16)a.y, (_Float16)a.z, (_Float16)a.w,
                        (_Float16)b.x, (_Float16)b.y, (_Float16)b.z, (_Float16)b.w};
        }
        *(f16x8*)(smem + (uint32_t)(r * 512 + s * 16)) = v;
    }

    // ---- t-invariant params: direct f32 scalar loads (was pk) ----
    float4 p0v[2], p1v[2], p2v[2]; float wo0[2], wo1[2];
    float bih[3][2], bh0[2];
    #pragma unroll
    for (int jt = 0; jt < 2; jt++) {
        int jc = jc0 + jt * 16 + l15;
        p0v[jt] = make_float4(W_ih[(size_t)jc * 258 + 256],
                              W_ih[(size_t)jc * 258 + 257],
                              W_ih[(size_t)(512 + jc) * 258 + 256],
                              W_ih[(size_t)(512 + jc) * 258 + 257]);
        p1v[jt] = make_float4(W_ih[(size_t)(1024 + jc) * 258 + 256],
                              W_ih[(size_t)(1024 + jc) * 258 + 257],
                              b_hh[jc], b_hh[512 + jc]);
        p2v[jt] = make_float4(b_hh[1024 + jc], W_out[jc], W_out[512 + jc], 0.f);
        wo0[jt] = p2v[jt].y; wo1[jt] = p2v[jt].z;
        bh0[jt] = b_h0[jc];
        #pragma unroll
        for (int g = 0; g < 3; g++) bih[g][jt] = b_ih[g * 512 + jc];
    }
    const float bo = b_out[lane & 1];
    // a0 params for t=0 prologue (d = lane&1)
    const float bia_d = b_ia[lane & 1];
    float4 wia_d = make_float4(W_ia[(lane & 1) * 4 + 0], W_ia[(lane & 1) * 4 + 1],
                               W_ia[(lane & 1) * 4 + 2], W_ia[(lane & 1) * 4 + 3]);

    uint32_t bbase[6];   // steady B (96 rows x 1024B) [validated swizzle]
    #pragma unroll
    for (int g = 0; g < 3; g++)
        #pragma unroll
        for (int jt = 0; jt < 2; jt++) {
            int r = g * 32 + jt * 16 + l15;
            bbase[g * 2 + jt] = BOFF + (uint32_t)r * 1024 +
                                ((uint32_t)(q2 ^ (r & 3)) << 4) +
                                ((uint32_t)((r >> 2) & 3) << 6);
        }
    uint32_t pb[8];      // pre-B (128 rows x 512B): 0..5 gates, 6..7 h0
    #pragma unroll
    for (int sl = 0; sl < 8; sl++) {
        int r = (sl < 6) ? ((sl >> 1) * 32 + (sl & 1) * 16 + l15)
                         : (96 + (sl - 6) * 16 + l15);
        pb[sl] = BOFF + (uint32_t)r * 512 +
                 ((uint32_t)(q2 ^ (r & 3)) << 4) +
                 ((uint32_t)((r >> 2) & 3) << 6);
    }
    __syncthreads();   // pre-B staged (ds_writes drained by barrier)

    // ---- pre-GEMM: K=256, A from z/x f32 (cvt in-register), 8 ks ----
    const int ia0 = M0g + (wv * 2 + 0) * 16 + l15;
    const int ia1 = M0g + (wv * 2 + 1) * 16 + l15;
    floatx4 accP[2][8];
    #pragma unroll
    for (int mt = 0; mt < 2; mt++)
        #pragma unroll
        for (int sl = 0; sl < 8; sl++) accP[mt][sl] = (floatx4){0.f, 0.f, 0.f, 0.f};
    {
        f16x8 aq[4][2];
        #define ALOADZ(S, KS) do { \
            aq[S][0] = ldzx8(z, x, ia0, (KS) * 32 + q2 * 8); \
            aq[S][1] = ldzx8(z, x, ia1, (KS) * 32 + q2 * 8); \
        } while (0)
        ALOADZ(0, 0); ALOADZ(1, 1); ALOADZ(2, 2);
        #pragma unroll
        for (int ks = 0; ks < 8; ks++) {
            if (ks < 5) { ALOADZ((ks + 3) & 3, ks + 3); }
            f16x8 a0 = aq[ks & 3][0];
            f16x8 a1 = aq[ks & 3][1];
            const uint32_t kadd = (uint32_t)((ks >> 2) << 8);
            const uint32_t kxor = (uint32_t)((ks & 3) << 6);
            #pragma unroll
            for (int sl = 0; sl < 8; sl++) {
                f16x8 b = *(const f16x8*)(smem + ((pb[sl] + kadd) ^ kxor));
                accP[0][sl] = __builtin_amdgcn_mfma_f32_16x16x32_f16(a0, b, accP[0][sl], 0, 0, 0);
                accP[1][sl] = __builtin_amdgcn_mfma_f32_16x16x32_f16(a1, b, accP[1][sl], 0, 0, 0);
            }
        }
        #undef ALOADZ
    }

    // ---- gi -> registers (+bias); h0 -> hstore [R15] ----
    float gi[2][3][2][4];
    #pragma unroll
    for (int mt = 0; mt < 2; mt++)
        #pragma unroll
        for (int g = 0; g < 3; g++)
            #pragma unroll
            for (int jt = 0; jt < 2; jt++)
                #pragma unroll
                for (int reg = 0; reg < 4; reg++)
                    gi[mt][g][jt][reg] = accP[mt][g * 2 + jt][reg] + bih[g][jt];
    #pragma unroll
    for (int mt = 0; mt < 2; mt++)
        #pragma unroll
        for (int jt = 0; jt < 2; jt++)
            #pragma unroll
            for (int reg = 0; reg < 4; reg++) {
                int rl = (wv * 2 + mt) * 16 + q2 * 4 + reg;
                float v = accP[mt][6 + jt][reg] + bh0[jt];
                *(_Float16*)(smem + HST + (uint32_t)(rl * 64 + (jt * 16 + l15) * 2)) = (_Float16)v;
            }
    __syncthreads();   // pre-B reads + hstore writes complete

    // ---- inline steady-B staging: 96 rows x 512 fp16 (1KB rows) from W_hh ----
    // LDS[r*1024 + l*16] = W_hh[nrow][ (l^(r&15))*8 ..+8 ] as fp16 (validated map).
    #pragma unroll
    for (int u = 0; u < 12; u++) {
        int sl2 = u * 512 + tid;            // 0..6143
        int r = sl2 >> 6, l = sl2 & 63;     // row 0..95, slot 0..63
        int nrow = (r >> 5) * 512 + jc0 + (r & 31);
        int c = (l ^ (r & 15)) << 3;
        const float4* src = (const float4*)(W_hh + (size_t)nrow * 512 + c);
        float4 a = src[0], b = src[1];
        f16x8 v = {(_Float16)a.x, (_Float16)a.y, (_Float16)a.z, (_Float16)a.w,
                   (_Float16)b.x, (_Float16)b.y, (_Float16)b.z, (_Float16)b.w};
        *(f16x8*)(smem + (uint32_t)(r * 1024 + l * 16)) = v;
    }
    // ---- publish h0 (block-major, contiguous own lines) [R15] ----
    {
        int row = tid >> 1, half = tid & 1;
        const char* sl = smem + HST + (uint32_t)(row * 64 + half * 32);
        char* gd = (char*)&g_h[0][0] + (size_t)gidx * 262144 + (size_t)cgrp * 16384 +
                   (size_t)row * 64 + (size_t)half * 32;
        *(f16x8*)gd = *(const f16x8*)sl;
        *(f16x8*)(gd + 16) = *(const f16x8*)(sl + 16);
    }
    group_barrier16(gidx);   // drains B ds_writes + h0 publish

    // ---- 12-step loop: R15 VERBATIM ----
    #pragma unroll 1
    for (int t = 0; t < 12; t++) {
        // warm next-step publish regions (RFO prefetch, overlapped with GEMM)
        if (t < 11 && wv == 0) {
            const char* wb = (const char*)&g_h[t + 1][0] + (size_t)gidx * 262144 +
                             (size_t)cgrp * 16384 + (size_t)lane * 128;
            async16(smem + DUM, wb);
            async16(smem + DUM, wb + 8192);
        }
        if (wv == 1) {
            const char* wp = (const char*)&g_P[t][0] +
                             ((size_t)gidx * 8192 + (size_t)cgrp * 512) * 4 +
                             (size_t)(lane & 15) * 128;
            async16(smem + DUM, wp);
        }

        // GEMM: K=512, A from g_h[t] (block-major: ks slab = 16KB)
        const char* hb = (const char*)&g_h[t][0] + (size_t)gidx * 262144 + (size_t)q2 * 16;
        const char* rp0 = hb + (size_t)((wv * 2 + 0) * 16 + l15) * 64;
        const char* rp1 = hb + (size_t)((wv * 2 + 1) * 16 + l15) * 64;
        floatx4 acc[2][3][2];
        #pragma unroll
        for (int mt = 0; mt < 2; mt++)
            #pragma unroll
            for (int g = 0; g < 3; g++)
                #pragma unroll
                for (int jt = 0; jt < 2; jt++)
                    acc[mt][g][jt] = (floatx4){0.f, 0.f, 0.f, 0.f};

        f16x8 aq[4][2];
        #define ALOAD(S, KS) do { \
            aq[S][0] = *(const f16x8*)(rp0 + (size_t)(KS) * 16384); \
            aq[S][1] = *(const f16x8*)(rp1 + (size_t)(KS) * 16384); \
        } while (0)
        ALOAD(0, 0); ALOAD(1, 1); ALOAD(2, 2);

        // prologue loads issued early (consumed after GEMM)
        float pv[16];
        if (t > 0) {
            const float* pbase = &g_P[t - 1][0] + (size_t)gidx * 8192 +
                                 (size_t)(wv * 32 + (lane >> 1)) * 2 + (size_t)(lane & 1);
            #pragma unroll
            for (int c = 0; c < 16; c++) pv[c] = pbase[c * 512];
        }

        #pragma unroll
        for (int ks = 0; ks < 16; ks++) {
            if (ks < 13) { ALOAD((ks + 3) & 3, ks + 3); }
            f16x8 a0 = aq[ks & 3][0];
            f16x8 a1 = aq[ks & 3][1];
            const uint32_t kadd = (uint32_t)((ks >> 2) << 8);
            const uint32_t kxor = (uint32_t)((ks & 3) << 6);
            #pragma unroll
            for (int g = 0; g < 3; g++)
                #pragma unroll
                for (int jt = 0; jt < 2; jt++) {
                    f16x8 b = *(const f16x8*)(smem + ((bbase[g * 2 + jt] + kadd) ^ kxor));
                    acc[0][g][jt] = __builtin_amdgcn_mfma_f32_16x16x32_f16(a0, b, acc[0][g][jt], 0, 0, 0);
                    acc[1][g][jt] = __builtin_amdgcn_mfma_f32_16x16x32_f16(a1, b, acc[1][g][jt], 0, 0, 0);
                }
        }
        #undef ALOAD

        // prologue finish (wave-private): x_t for wave's 32 rows
        {
            float v;
            if (t == 0) {
                int i = M0g + wv * 32 + (lane >> 1);
                float4 xr = *(const float4*)(x0 + (size_t)i * 4);
                v = bia_d + xr.x * wia_d.x + xr.y * wia_d.y +
                            xr.z * wia_d.z + xr.w * wia_d.w;
            } else {
                v = bo;
                #pragma unroll
                for (int c = 0; c < 16; c++) v += pv[c];
                douts[wv * 768 + (t - 1) * 64 + lane] = v;   // stash out_{t-1}
            }
            xs[wv * 64 + lane] = v;
        }

        // epilogue (wave-private rows): gates, hn -> hstore, reduce -> g_P[t]
        #pragma unroll
        for (int mt = 0; mt < 2; mt++) {
            float po[4][2];
            #pragma unroll
            for (int reg = 0; reg < 4; reg++) { po[reg][0] = 0.f; po[reg][1] = 0.f; }
            #pragma unroll
            for (int jt = 0; jt < 2; jt++) {
                #pragma unroll
                for (int reg = 0; reg < 4; reg++) {
                    int local = mt * 16 + q2 * 4 + reg;        // 0..31 in wave
                    int rl = wv * 32 + local;                  // 0..255 in block
                    float2 xv = *(const float2*)(smem + XSO + (uint32_t)((wv * 64 + local * 2) * 4));
                    _Float16* hp = (_Float16*)(smem + HST + (uint32_t)(rl * 64 + (jt * 16 + l15) * 2));
                    float hold = (float)hp[0];
                    float r  = sigm_f(gi[mt][0][jt][reg] + p0v[jt].x * xv.x + p0v[jt].y * xv.y + acc[mt][0][jt][reg] + p1v[jt].z);
                    float u  = sigm_f(gi[mt][1][jt][reg] + p0v[jt].z * xv.x + p0v[jt].w * xv.y + acc[mt][1][jt][reg] + p1v[jt].w);
                    float nn = tanh_f(gi[mt][2][jt][reg] + p1v[jt].x * xv.x + p1v[jt].y * xv.y + r * (acc[mt][2][jt][reg] + p2v[jt].x));
                    float hn = (1.f - u) * nn + u * hold;
                    hp[0] = (_Float16)hn;
                    po[reg][0] += hn * wo0[jt];
                    po[reg][1] += hn * wo1[jt];
                }
            }
            #pragma unroll
            for (int m = 1; m < 16; m <<= 1)
                #pragma unroll
                for (int reg = 0; reg < 4; reg++) {
                    po[reg][0] += __shfl_xor(po[reg][0], m);
                    po[reg][1] += __shfl_xor(po[reg][1], m);
                }
            if (l15 == 0) {
                #pragma unroll
                for (int reg = 0; reg < 4; reg++) {
                    int local = mt * 16 + q2 * 4 + reg;
                    float* pp = &g_P[t][0] + (size_t)gidx * 8192 + (size_t)cgrp * 512 +
                                (size_t)(wv * 32 + local) * 2;
                    *(float2*)pp = make_float2(po[reg][0], po[reg][1]);
                }
            }
        }

        // publish h (wave-private 2KB slice, block-major contiguous)
        if (t < 11) {
            int rloc = wv * 32 + (lane >> 1);
            int half = lane & 1;
            const char* sl = smem + HST + (uint32_t)(rloc * 64 + half * 32);
            char* gd = (char*)&g_h[t + 1][0] + (size_t)gidx * 262144 +
                       (size_t)cgrp * 16384 + (size_t)rloc * 64 + (size_t)half * 32;
            *(f16x8*)gd = *(const f16x8*)sl;
            *(f16x8*)(gd + 16) = *(const f16x8*)(sl + 16);
        }
        group_barrier16(gidx);
    }

    // ---- final: out_11 + dout flush (cgrp 0 blocks only) [R15] ----
    if (cgrp == 0) {
        const float* pbase = &g_P[11][0] + (size_t)gidx * 8192 +
                             (size_t)(wv * 32 + (lane >> 1)) * 2 + (size_t)(lane & 1);
        float v = bo;
        #pragma unroll
        for (int c = 0; c < 16; c++) v += pbase[c * 512];
        douts[wv * 768 + 11 * 64 + lane] = v;
        size_t i = (size_t)(M0g + wv * 32 + (lane >> 1));
        int d = lane & 1;
        #pragma unroll
        for (int t = 0; t < 12; t++)
            dout[(i * 12 + t) * 2 + d] = douts[wv * 768 + t * 64 + lane];
    }
}

extern "C" void kernel_launch(void* const* d_in, const int* in_sizes, int n_in,
                              void* d_out, int out_size, void* d_ws, size_t ws_size,
                              hipStream_t stream)
{
    const float* z     = (const float*)d_in[0];
    const float* x     = (const float*)d_in[1];
    const float* x0    = (const float*)d_in[2];
    const float* W_ia  = (const float*)d_in[3];
    const float* b_ia  = (const float*)d_in[4];
    const float* W_h0  = (const float*)d_in[5];
    const float* b_h0  = (const float*)d_in[6];
    const float* W_ih  = (const float*)d_in[7];
    const float* b_ih  = (const float*)d_in[8];
    const float* W_hh  = (const float*)d_in[9];
    const float* b_hh  = (const float*)d_in[10];
    const float* W_out = (const float*)d_in[11];
    const float* b_out = (const float*)d_in[12];
    float* dout = (float*)d_out;

    static bool s_attr_done = false;
    if (!s_attr_done) {
        hipFuncSetAttribute((const void*)k_all,
                            hipFuncAttributeMaxDynamicSharedMemorySize, 142400);
        s_attr_done = true;
    }

    k_all<<<256, 512, 142400, stream>>>(z, x, x0, W_ia, b_ia, W_h0, b_h0,
                                        W_ih, b_ih, W_hh, b_hh, W_out, b_out,
                                        dout);
}